// Round 11
// baseline (219.777 us; speedup 1.0000x reference)
//
#include <hip/hip_runtime.h>
#include <hip/hip_bf16.h>

#define BATCH 128
#define DIM   1024
#define BD    (BATCH*DIM)          // 131072
#define CSZ   ((size_t)BD*DIM)     // 134217728

typedef float vf4 __attribute__((ext_vector_type(4)));

__device__ __forceinline__ float sigmoidf_(float z){ return 1.0f/(1.0f+expf(-z)); }
__device__ __forceinline__ float dot4(float4 a, float4 b){
  return a.x*b.x + a.y*b.y + a.z*b.z + a.w*b.w;
}

// ---------------- kernel 1: fused 4-matrix GEMM, split-K ---------------------
// block tile 128(M)x64(N), thread tile 8x4, K chunk 16. grid = 64*KS blocks.
// x tile stored TRANSPOSED in LDS -> inner loop reads 2x ds_read_b128 for x.
__global__ __launch_bounds__(256) void gemm_k(
    const float* __restrict__ x,
    const float* __restrict__ w0, const float* __restrict__ w1,
    const float* __restrict__ w2, const float* __restrict__ w3,
    float* __restrict__ part, int KS){
  __shared__ float xst[16][132];  // [k][row], stride 132 (mod 32 = 4)
  __shared__ float wsh[16][64];
  const int bx  = blockIdx.x;
  const int ks  = bx >> 6;
  const int ct  = bx & 63;
  const int m   = ct >> 4;        // matrix id
  const int cb  = ct & 15;        // 64-wide col block within matrix
  const float* W = (m==0) ? w0 : (m==1) ? w1 : (m==2) ? w2 : w3;
  const int Ksub = DIM / KS;
  const int kb   = ks * Ksub;
  const int tid  = threadIdx.x;
  const int cc = tid & 15, rr = tid >> 4;

  float acc[8][4];
  #pragma unroll
  for(int i=0;i<8;i++)
    #pragma unroll
    for(int j=0;j<4;j++) acc[i][j] = 0.0f;

  for(int kk = 0; kk < Ksub; kk += 16){
    #pragma unroll
    for(int jj=0;jj<2;jj++){
      const int l = tid + jj*256;
      const int row = l >> 2, kc = (l & 3) * 4;
      const float4 v = *(const float4*)(x + row*DIM + kb + kk + kc);
      xst[kc+0][row]=v.x; xst[kc+1][row]=v.y; xst[kc+2][row]=v.z; xst[kc+3][row]=v.w;
    }
    {
      const int kr = tid >> 4, c = (tid & 15) * 4;
      *(float4*)&wsh[kr][c] =
          *(const float4*)(W + (size_t)(kb + kk + kr)*DIM + cb*64 + c);
    }
    __syncthreads();
    #pragma unroll
    for(int t=0;t<16;t++){
      const float4 wa = *(const float4*)&wsh[t][cc*4];
      const float4 xa = *(const float4*)&xst[t][rr*8];
      const float4 xb = *(const float4*)&xst[t][rr*8+4];
      float xr[8];
      xr[0]=xa.x; xr[1]=xa.y; xr[2]=xa.z; xr[3]=xa.w;
      xr[4]=xb.x; xr[5]=xb.y; xr[6]=xb.z; xr[7]=xb.w;
      #pragma unroll
      for(int i=0;i<8;i++){
        acc[i][0] += xr[i]*wa.x; acc[i][1] += xr[i]*wa.y;
        acc[i][2] += xr[i]*wa.z; acc[i][3] += xr[i]*wa.w;
      }
    }
    __syncthreads();
  }

  float* po = part + (size_t)(ks*4 + m) * BD;
  #pragma unroll
  for(int i=0;i<8;i++){
    const int row = rr*8 + i;
    __builtin_nontemporal_store(
        (vf4){acc[i][0],acc[i][1],acc[i][2],acc[i][3]},
        (vf4*)(po + row*DIM + cb*64 + cc*4));
  }
}

// ---------------- kernel 2: split-K combine + bias + activations ------------
__global__ void combine_k(const float* __restrict__ part,
                          const float* __restrict__ bq, const float* __restrict__ bk,
                          const float* __restrict__ bv, const float* __restrict__ bo,
                          float* __restrict__ qkvo, int KS){
  const int gid  = blockIdx.x*blockDim.x + threadIdx.x;  // 0..131071
  const int flat = gid * 4;
  const int m    = flat >> 17;          // matrix id (uniform per block)
  const int idx  = flat & (BD - 1);
  const int c    = idx & (DIM - 1);
  vf4 s = (vf4){0.f,0.f,0.f,0.f};
  for(int ks=0; ks<KS; ks++){
    s += __builtin_nontemporal_load((const vf4*)(part + (size_t)(ks*4+m)*BD + idx));
  }
  const float* bp = (m==0) ? bq : (m==1) ? bk : (m==2) ? bv : bo;
  const vf4 bb = *(const vf4*)(bp + c);
  s += bb;
  if(m == 1){ // k scaled by 1/sqrt(d)
    s *= 0.03125f;
  } else if(m == 3){ // o gate
    s.x = sigmoidf_(s.x); s.y = sigmoidf_(s.y);
    s.z = sigmoidf_(s.z); s.w = sigmoidf_(s.w);
  }
  *(vf4*)(qkvo + (size_t)m*BD + idx) = s;
}

// ---------------- kernel 3: fused scalar gates + n_t + den ------------------
__global__ void gfnd_k(const float* __restrict__ x,  const float* __restrict__ wi,
                       const float* __restrict__ bi, const float* __restrict__ wf,
                       const float* __restrict__ bf, const float* __restrict__ qkvo,
                       const float* __restrict__ nprev,
                       float* __restrict__ gI, float* __restrict__ gF,
                       float* __restrict__ nout, float* __restrict__ gD){
  __shared__ float red[8];
  __shared__ float sif[2];
  const int b = blockIdx.x, tid = threadIdx.x;
  const float4 xv  = *(const float4*)(x  + b*DIM + tid*4);
  const float4 wi4 = *(const float4*)(wi + tid*4);
  const float4 wf4 = *(const float4*)(wf + tid*4);
  float si = dot4(xv, wi4);
  float sf = dot4(xv, wf4);
  #pragma unroll
  for(int off=32; off; off>>=1){ si += __shfl_xor(si,off); sf += __shfl_xor(sf,off); }
  if((tid & 63) == 0){ red[tid>>6] = si; red[4+(tid>>6)] = sf; }
  __syncthreads();
  if(tid == 0){
    float a = red[0]+red[1]+red[2]+red[3];
    float c = red[4]+red[5]+red[6]+red[7];
    float itv = expf(a + bi[0]);
    float ftv = sigmoidf_(c + bf[0]);
    gI[b] = itv; gF[b] = ftv; sif[0] = itv; sif[1] = ftv;
  }
  __syncthreads();
  const float it = sif[0], ft = sif[1];
  const float4 q4 = *(const float4*)(qkvo +      b*DIM + tid*4);
  const float4 k4 = *(const float4*)(qkvo + BD + b*DIM + tid*4);
  const float4 np = *(const float4*)(nprev +     b*DIM + tid*4);
  float4 n4;
  n4.x = ft*np.x + it*k4.x; n4.y = ft*np.y + it*k4.y;
  n4.z = ft*np.z + it*k4.z; n4.w = ft*np.w + it*k4.w;
  __builtin_nontemporal_store((vf4){n4.x,n4.y,n4.z,n4.w}, (vf4*)(nout + b*DIM + tid*4));
  float s = dot4(n4, q4);
  #pragma unroll
  for(int off=32; off; off>>=1) s += __shfl_xor(s, off);
  if((tid & 63) == 0) red[tid>>6] = s;
  __syncthreads();
  if(tid == 0) gD[b] = fmaxf(fabsf(red[0]+red[1]+red[2]+red[3]), 1.0f);
}

// ---------------- kernel 4: C_t stream + fused num reduce + h_t -------------
// R11: 1 row/wave (grid 32768, 4 rows/block), one-shot body. Minimal VGPR
// footprint (cc[4]+qv[4]+kv[4] ~ 48 data regs) targeting the <=64-VGPR
// occupancy bracket (8 waves/SIMD). NT-ld + NT-st (pinned best).
__global__ __launch_bounds__(256) void cell_k(
    const float* __restrict__ Cp, float* __restrict__ Co,
    const float* __restrict__ qkvo,
    const float* __restrict__ gI, const float* __restrict__ gF,
    const float* __restrict__ gD, float* __restrict__ hout){
  const int tid  = threadIdx.x;
  const int lane = tid & 63;
  const int wr   = blockIdx.x * 4 + (tid >> 6);  // this wave's row (4 | 1024 -> same b per block)
  const int b    = wr >> 10;
  const int d0   = wr & (DIM - 1);
  const float ft = gF[b], it = gI[b];
  const float rden = 1.0f / gD[b];
  const float* qb = qkvo +        b*DIM;
  const float* kb = qkvo + BD +   b*DIM;
  const float iv = it * qkvo[2*BD + b*DIM + d0];
  const float ov = qkvo[3*BD + b*DIM + d0];
  const size_t base = (size_t)wr * DIM;

  vf4 cc[4], qv[4], kv[4];
  // ---- phase 1: issue all loads (12 in flight per wave) ----
  #pragma unroll
  for(int t=0;t<4;t++){
    const int e = (t<<8) + (lane<<2);
    qv[t] = *(const vf4*)(qb + e);
    kv[t] = *(const vf4*)(kb + e);
    cc[t] = __builtin_nontemporal_load((const vf4*)(Cp + base + e));
  }
  // ---- phase 2: compute + store + dot ----
  float a0 = 0.f;
  #pragma unroll
  for(int t=0;t<4;t++){
    const int e = (t<<8) + (lane<<2);
    const vf4 t0 = ft*cc[t] + iv*kv[t];
    __builtin_nontemporal_store(t0, (vf4*)(Co + base + e));
    a0 += t0.x*qv[t].x + t0.y*qv[t].y + t0.z*qv[t].z + t0.w*qv[t].w;
  }
  #pragma unroll
  for(int off=32; off; off>>=1) a0 += __shfl_xor(a0, off);
  if(lane == 0) hout[wr] = ov * a0 * rden;
}

extern "C" void kernel_launch(void* const* d_in, const int* in_sizes, int n_in,
                              void* d_out, int out_size, void* d_ws, size_t ws_size,
                              hipStream_t stream){
  const float* x  = (const float*)d_in[0];
  const float* Cp = (const float*)d_in[1];
  const float* np = (const float*)d_in[2];
  const float* Wq = (const float*)d_in[3];  const float* bq = (const float*)d_in[4];
  const float* Wk = (const float*)d_in[5];  const float* bk = (const float*)d_in[6];
  const float* Wv = (const float*)d_in[7];  const float* bv = (const float*)d_in[8];
  const float* Wo = (const float*)d_in[9];  const float* bo = (const float*)d_in[10];
  const float* wi = (const float*)d_in[11]; const float* bi = (const float*)d_in[12];
  const float* wf = (const float*)d_in[13]; const float* bf = (const float*)d_in[14];

  float* out  = (float*)d_out;
  float* hout = out;                 // [128,1024]
  float* Cout = out + BD;            // [128,1024,1024]
  float* nout = out + BD + CSZ;      // [128,1024]

  // workspace layout: [KS*4*BD partials][4*BD qkvo][128 gI][128 gF][128 gD]
  int KS = 8;
  size_t need8 = ((size_t)8*4*BD + 4*BD + 384) * 4;
  size_t need2 = ((size_t)2*4*BD + 4*BD + 384) * 4;
  if(ws_size >= need8)      KS = 8;
  else if(ws_size >= need2) KS = 2;
  else                      KS = 1;

  float* part = (float*)d_ws;
  float* qkvo = part + (size_t)KS*4*BD;
  float* gI   = qkvo + (size_t)4*BD;
  float* gF   = gI + BATCH;
  float* gD   = gF + BATCH;

  gemm_k   <<<64*KS, 256, 0, stream>>>(x, Wq, Wk, Wv, Wo, part, KS);
  combine_k<<<512,   256, 0, stream>>>(part, bq, bk, bv, bo, qkvo, KS);
  gfnd_k   <<<BATCH, 256, 0, stream>>>(x, wi, bi, wf, bf, qkvo, np, gI, gF, nout, gD);
  cell_k   <<<32768, 256, 0, stream>>>(Cp, Cout, qkvo, gI, gF, gD, hout);
}

// Round 12
// 209.317 us; speedup vs baseline: 1.0500x; 1.0500x over previous
//
#include <hip/hip_runtime.h>
#include <hip/hip_bf16.h>

#define BATCH 128
#define DIM   1024
#define BD    (BATCH*DIM)          // 131072
#define CSZ   ((size_t)BD*DIM)     // 134217728

typedef float vf4 __attribute__((ext_vector_type(4)));

__device__ __forceinline__ float sigmoidf_(float z){ return 1.0f/(1.0f+expf(-z)); }
__device__ __forceinline__ float dot4(float4 a, float4 b){
  return a.x*b.x + a.y*b.y + a.z*b.z + a.w*b.w;
}

// ---------------- kernel 1: fused 4-matrix GEMM, split-K ---------------------
// block tile 128(M)x64(N), thread tile 8x4, K chunk 16. grid = 64*KS blocks.
// part stores REGULAR (R12): 16MB producer->consumer intermediate should ride
// L2/L3, not HBM (NT was wrong here — NT is for the 512MB streams only).
__global__ __launch_bounds__(256) void gemm_k(
    const float* __restrict__ x,
    const float* __restrict__ w0, const float* __restrict__ w1,
    const float* __restrict__ w2, const float* __restrict__ w3,
    float* __restrict__ part, int KS){
  __shared__ float xst[16][132];  // [k][row], stride 132 (mod 32 = 4)
  __shared__ float wsh[16][64];
  const int bx  = blockIdx.x;
  const int ks  = bx >> 6;
  const int ct  = bx & 63;
  const int m   = ct >> 4;        // matrix id
  const int cb  = ct & 15;        // 64-wide col block within matrix
  const float* W = (m==0) ? w0 : (m==1) ? w1 : (m==2) ? w2 : w3;
  const int Ksub = DIM / KS;
  const int kb   = ks * Ksub;
  const int tid  = threadIdx.x;
  const int cc = tid & 15, rr = tid >> 4;

  float acc[8][4];
  #pragma unroll
  for(int i=0;i<8;i++)
    #pragma unroll
    for(int j=0;j<4;j++) acc[i][j] = 0.0f;

  for(int kk = 0; kk < Ksub; kk += 16){
    #pragma unroll
    for(int jj=0;jj<2;jj++){
      const int l = tid + jj*256;
      const int row = l >> 2, kc = (l & 3) * 4;
      const float4 v = *(const float4*)(x + row*DIM + kb + kk + kc);
      xst[kc+0][row]=v.x; xst[kc+1][row]=v.y; xst[kc+2][row]=v.z; xst[kc+3][row]=v.w;
    }
    {
      const int kr = tid >> 4, c = (tid & 15) * 4;
      *(float4*)&wsh[kr][c] =
          *(const float4*)(W + (size_t)(kb + kk + kr)*DIM + cb*64 + c);
    }
    __syncthreads();
    #pragma unroll
    for(int t=0;t<16;t++){
      const float4 wa = *(const float4*)&wsh[t][cc*4];
      const float4 xa = *(const float4*)&xst[t][rr*8];
      const float4 xb = *(const float4*)&xst[t][rr*8+4];
      float xr[8];
      xr[0]=xa.x; xr[1]=xa.y; xr[2]=xa.z; xr[3]=xa.w;
      xr[4]=xb.x; xr[5]=xb.y; xr[6]=xb.z; xr[7]=xb.w;
      #pragma unroll
      for(int i=0;i<8;i++){
        acc[i][0] += xr[i]*wa.x; acc[i][1] += xr[i]*wa.y;
        acc[i][2] += xr[i]*wa.z; acc[i][3] += xr[i]*wa.w;
      }
    }
    __syncthreads();
  }

  float* po = part + (size_t)(ks*4 + m) * BD;
  #pragma unroll
  for(int i=0;i<8;i++){
    const int row = rr*8 + i;
    *(float4*)(po + row*DIM + cb*64 + cc*4) =
        make_float4(acc[i][0],acc[i][1],acc[i][2],acc[i][3]);
  }
}

// ---------------- kernel 2: split-K combine + bias + activations ------------
// part loads REGULAR (R12): hits L2/L3 where gemm's regular stores landed.
__global__ void combine_k(const float* __restrict__ part,
                          const float* __restrict__ bq, const float* __restrict__ bk,
                          const float* __restrict__ bv, const float* __restrict__ bo,
                          float* __restrict__ qkvo, int KS){
  const int gid  = blockIdx.x*blockDim.x + threadIdx.x;  // 0..131071
  const int flat = gid * 4;
  const int m    = flat >> 17;          // matrix id (uniform per block)
  const int idx  = flat & (BD - 1);
  const int c    = idx & (DIM - 1);
  vf4 s = (vf4){0.f,0.f,0.f,0.f};
  for(int ks=0; ks<KS; ks++){
    s += *(const vf4*)(part + (size_t)(ks*4+m)*BD + idx);
  }
  const float* bp = (m==0) ? bq : (m==1) ? bk : (m==2) ? bv : bo;
  const vf4 bb = *(const vf4*)(bp + c);
  s += bb;
  if(m == 1){ // k scaled by 1/sqrt(d)
    s *= 0.03125f;
  } else if(m == 3){ // o gate
    s.x = sigmoidf_(s.x); s.y = sigmoidf_(s.y);
    s.z = sigmoidf_(s.z); s.w = sigmoidf_(s.w);
  }
  *(vf4*)(qkvo + (size_t)m*BD + idx) = s;
}

// ---------------- kernel 3: fused scalar gates + n_t + den ------------------
__global__ void gfnd_k(const float* __restrict__ x,  const float* __restrict__ wi,
                       const float* __restrict__ bi, const float* __restrict__ wf,
                       const float* __restrict__ bf, const float* __restrict__ qkvo,
                       const float* __restrict__ nprev,
                       float* __restrict__ gI, float* __restrict__ gF,
                       float* __restrict__ nout, float* __restrict__ gD){
  __shared__ float red[8];
  __shared__ float sif[2];
  const int b = blockIdx.x, tid = threadIdx.x;
  const float4 xv  = *(const float4*)(x  + b*DIM + tid*4);
  const float4 wi4 = *(const float4*)(wi + tid*4);
  const float4 wf4 = *(const float4*)(wf + tid*4);
  float si = dot4(xv, wi4);
  float sf = dot4(xv, wf4);
  #pragma unroll
  for(int off=32; off; off>>=1){ si += __shfl_xor(si,off); sf += __shfl_xor(sf,off); }
  if((tid & 63) == 0){ red[tid>>6] = si; red[4+(tid>>6)] = sf; }
  __syncthreads();
  if(tid == 0){
    float a = red[0]+red[1]+red[2]+red[3];
    float c = red[4]+red[5]+red[6]+red[7];
    float itv = expf(a + bi[0]);
    float ftv = sigmoidf_(c + bf[0]);
    gI[b] = itv; gF[b] = ftv; sif[0] = itv; sif[1] = ftv;
  }
  __syncthreads();
  const float it = sif[0], ft = sif[1];
  const float4 q4 = *(const float4*)(qkvo +      b*DIM + tid*4);
  const float4 k4 = *(const float4*)(qkvo + BD + b*DIM + tid*4);
  const float4 np = *(const float4*)(nprev +     b*DIM + tid*4);
  float4 n4;
  n4.x = ft*np.x + it*k4.x; n4.y = ft*np.y + it*k4.y;
  n4.z = ft*np.z + it*k4.z; n4.w = ft*np.w + it*k4.w;
  __builtin_nontemporal_store((vf4){n4.x,n4.y,n4.z,n4.w}, (vf4*)(nout + b*DIM + tid*4));
  float s = dot4(n4, q4);
  #pragma unroll
  for(int off=32; off; off>>=1) s += __shfl_xor(s, off);
  if((tid & 63) == 0) red[tid>>6] = s;
  __syncthreads();
  if(tid == 0) gD[b] = fmaxf(fabsf(red[0]+red[1]+red[2]+red[3]), 1.0f);
}

// ---------------- kernel 4: C_t stream + fused num reduce + h_t -------------
// R10 config (measured best, 218.1us): 8 rows/block (grid 16384), 2 rows/wave,
// ONE-SHOT body (loops serialize on in-order vmcnt store drain — R9). Small
// footprint -> high occupancy TLP. NT-ld + NT-st (pinned by R5/R8 A/Bs).
__global__ __launch_bounds__(256) void cell_k(
    const float* __restrict__ Cp, float* __restrict__ Co,
    const float* __restrict__ qkvo,
    const float* __restrict__ gI, const float* __restrict__ gF,
    const float* __restrict__ gD, float* __restrict__ hout){
  const int tid  = threadIdx.x;
  const int lane = tid & 63;
  const int r0   = blockIdx.x * 8;           // 8 rows/block, all same b
  const int b    = r0 >> 10;
  const int wr0  = r0 + ((tid >> 6) << 1);   // this wave's 2 rows
  const int d0   = wr0 & (DIM - 1);
  const float ft = gF[b], it = gI[b];
  const float rden = 1.0f / gD[b];
  const float* qb = qkvo +        b*DIM;
  const float* kb = qkvo + BD +   b*DIM;
  const float* vb = qkvo + 2*BD + b*DIM;
  const float* ob = qkvo + 3*BD + b*DIM;
  const float iv0 = it*vb[d0], iv1 = it*vb[d0+1];
  const size_t base = (size_t)wr0 * DIM;

  vf4 cc[8], qv[4], kv[4];
  // ---- phase 1: issue all loads (16 in flight per wave) ----
  #pragma unroll
  for(int t=0;t<4;t++){
    const int e = (t<<8) + (lane<<2);
    qv[t] = *(const vf4*)(qb + e);
    kv[t] = *(const vf4*)(kb + e);
    cc[t*2+0] = __builtin_nontemporal_load((const vf4*)(Cp + base +       e));
    cc[t*2+1] = __builtin_nontemporal_load((const vf4*)(Cp + base + DIM + e));
  }
  // ---- phase 2: compute + store + dot ----
  float a0=0.f, a1=0.f;
  #pragma unroll
  for(int t=0;t<4;t++){
    const int e = (t<<8) + (lane<<2);
    const vf4 q4 = qv[t], k4 = kv[t];
    const vf4 t0 = ft*cc[t*2+0] + iv0*k4;
    const vf4 t1 = ft*cc[t*2+1] + iv1*k4;
    __builtin_nontemporal_store(t0, (vf4*)(Co + base +       e));
    __builtin_nontemporal_store(t1, (vf4*)(Co + base + DIM + e));
    a0 += t0.x*q4.x + t0.y*q4.y + t0.z*q4.z + t0.w*q4.w;
    a1 += t1.x*q4.x + t1.y*q4.y + t1.z*q4.z + t1.w*q4.w;
  }
  #pragma unroll
  for(int off=32; off; off>>=1){
    a0 += __shfl_xor(a0, off); a1 += __shfl_xor(a1, off);
  }
  if(lane == 0){
    float2 h;
    h.x = ob[d0+0]*a0*rden; h.y = ob[d0+1]*a1*rden;
    *(float2*)(hout + wr0) = h;
  }
}

extern "C" void kernel_launch(void* const* d_in, const int* in_sizes, int n_in,
                              void* d_out, int out_size, void* d_ws, size_t ws_size,
                              hipStream_t stream){
  const float* x  = (const float*)d_in[0];
  const float* Cp = (const float*)d_in[1];
  const float* np = (const float*)d_in[2];
  const float* Wq = (const float*)d_in[3];  const float* bq = (const float*)d_in[4];
  const float* Wk = (const float*)d_in[5];  const float* bk = (const float*)d_in[6];
  const float* Wv = (const float*)d_in[7];  const float* bv = (const float*)d_in[8];
  const float* Wo = (const float*)d_in[9];  const float* bo = (const float*)d_in[10];
  const float* wi = (const float*)d_in[11]; const float* bi = (const float*)d_in[12];
  const float* wf = (const float*)d_in[13]; const float* bf = (const float*)d_in[14];

  float* out  = (float*)d_out;
  float* hout = out;                 // [128,1024]
  float* Cout = out + BD;            // [128,1024,1024]
  float* nout = out + BD + CSZ;      // [128,1024]

  // workspace layout: [KS*4*BD partials][4*BD qkvo][128 gI][128 gF][128 gD]
  int KS = 8;
  size_t need8 = ((size_t)8*4*BD + 4*BD + 384) * 4;
  size_t need2 = ((size_t)2*4*BD + 4*BD + 384) * 4;
  if(ws_size >= need8)      KS = 8;
  else if(ws_size >= need2) KS = 2;
  else                      KS = 1;

  float* part = (float*)d_ws;
  float* qkvo = part + (size_t)KS*4*BD;
  float* gI   = qkvo + (size_t)4*BD;
  float* gF   = gI + BATCH;
  float* gD   = gF + BATCH;

  gemm_k   <<<64*KS, 256, 0, stream>>>(x, Wq, Wk, Wv, Wo, part, KS);
  combine_k<<<512,   256, 0, stream>>>(part, bq, bk, bv, bo, qkvo, KS);
  gfnd_k   <<<BATCH, 256, 0, stream>>>(x, wi, bi, wf, bf, qkvo, np, gI, gF, nout, gD);
  cell_k   <<<16384, 256, 0, stream>>>(Cp, Cout, qkvo, gI, gF, gD, hout);
}